// Round 5
// baseline (2863.240 us; speedup 1.0000x reference)
//
#include <hip/hip_runtime.h>

#define IMG_N   8
#define IMG_H   512
#define IMG_W   512
#define BLK     32
#define P_CNT   256
#define PSFN    64
#define SENS    1024

#define WPSTRIDE 132          // paired-row weight layout (see R2-R4)
#define SJ       129          // LDS tile row stride (pad: 2-way banks = free)
#define TI       127
#define TJ       128
#define TILE_FLOATS (TI * TJ) // 16256
#define UNION_FLOATS (TI * SJ) // 16383 floats; overlays WpT2 (5280 floats)
#define WS_NEED ((size_t)IMG_N * P_CNT * TILE_FLOATS * sizeof(float))

// Wreg2[q] (q 0..32), loaded from pairs 3..35 at acol=lane+1:
//   .x = Wp[a=lane][b=2q-2], .y = Wp[a=lane][b=2q-1]
template<int B>
__device__ __forceinline__ float wsel(const float2 (&w)[33]) {
    if constexpr (B & 1) return w[(B + 1) / 2].y;   // odd b (incl. b=-1)
    else                 return w[(B + 2) / 2].x;   // even b
}

template<int J, int C, int CEND>
struct ColFMA {
    static __device__ __forceinline__ void run(const float (&brow)[32],
                                               const float2 (&w)[33], float& acc) {
        acc = fmaf(brow[C], wsel<2 * C + 63 - J>(w), acc);
        ColFMA<J, C + 1, CEND>::run(brow, w, acc);
    }
};
template<int J, int CEND>
struct ColFMA<J, CEND, CEND> {
    static __device__ __forceinline__ void run(const float (&)[32],
                                               const float2 (&)[33], float&) {}
};

// out[i][j] needs c with b = 2c+63-j in [-1,63] -> c in [ceil((j-64)/2), j/2]
template<int J>
__device__ __forceinline__ float col_acc(const float (&brow)[32], const float2 (&w)[33]) {
    constexpr int CMINr = (J - 63) / 2;             // == ceil((J-64)/2) for J>63
    constexpr int CMIN  = CMINr < 0 ? 0 : CMINr;
    constexpr int CMAXr = J / 2;
    constexpr int CMAX  = CMAXr > 31 ? 31 : CMAXr;
    float acc = 0.0f;
    if constexpr (CMIN <= CMAX)
        ColFMA<J, CMIN, CMAX + 1>::run(brow, w, acc);
    return acc;
}

template<int JB>   // j-block: j = JB*8 + jj
__device__ __forceinline__ void do_jblock(const float (&brow)[32], const float2 (&w)[33],
                                          float* __restrict__ rowp) {
    float a0 = col_acc<JB * 8 + 0>(brow, w);
    float a1 = col_acc<JB * 8 + 1>(brow, w);
    float a2 = col_acc<JB * 8 + 2>(brow, w);
    float a3 = col_acc<JB * 8 + 3>(brow, w);
    float a4 = col_acc<JB * 8 + 4>(brow, w);
    float a5 = col_acc<JB * 8 + 5>(brow, w);
    float a6 = col_acc<JB * 8 + 6>(brow, w);
    float a7 = col_acc<JB * 8 + 7>(brow, w);
    atomicAdd(&rowp[JB * 8 + 0], a0);   // ds_add_f32: LDS atomic, no return
    atomicAdd(&rowp[JB * 8 + 1], a1);
    atomicAdd(&rowp[JB * 8 + 2], a2);
    atomicAdd(&rowp[JB * 8 + 3], a3);
    atomicAdd(&rowp[JB * 8 + 4], a4);
    atomicAdd(&rowp[JB * 8 + 5], a5);
    atomicAdd(&rowp[JB * 8 + 6], a6);
    atomicAdd(&rowp[JB * 8 + 7], a7);
}

// lane <-> PSF row a = lane (always valid -> zero waste, no divergence,
// no shuffles). At r-step, lane accumulates output row i = 2r+63-lane.
// j-blocks {WV, WV+4, WV+8, WV+12}: exactly 520 FMA/wave/r (balanced).
template<int WV>
__device__ __forceinline__ void main_loop(float* __restrict__ U,
                                          const float* __restrict__ blk_s,
                                          const float2 (&w)[33], int lane) {
    int rowoff = (63 - lane) * SJ;
    for (int r = 0; r < 32; ++r) {
        float brow[32];
        #pragma unroll
        for (int c4 = 0; c4 < 8; ++c4) {
            const float4 v = *(const float4*)&blk_s[r * 32 + c4 * 4];
            brow[c4 * 4 + 0] = v.x; brow[c4 * 4 + 1] = v.y;
            brow[c4 * 4 + 2] = v.z; brow[c4 * 4 + 3] = v.w;
        }
        float* rowp = &U[rowoff];
        do_jblock<WV +  0>(brow, w, rowp);
        do_jblock<WV +  4>(brow, w, rowp);
        do_jblock<WV +  8>(brow, w, rowp);
        do_jblock<WV + 12>(brow, w, rowp);
        rowoff += 2 * SJ;
    }
}

__global__ __launch_bounds__(256, 2) void svconv_tiles(
    const float* __restrict__ imgs, const float* __restrict__ psf,
    float* __restrict__ ws, float* __restrict__ out, const int use_ws)
{
    __shared__ float U[UNION_FLOATS];   // WpT2 during setup, then 127x129 outacc
    __shared__ float blk_s[BLK * BLK];
    __shared__ float garr[192];         // ghost (a=-1) weight line, zero-padded

    const int bid = blockIdx.x;
    const int n = bid >> 8;
    const int p = bid & 255;
    const int bh = p & 15;              // pairs with i / X axis
    const int bw = p >> 4;              // pairs with j / Y axis
    const int tid = threadIdx.x;
    const int wv = tid >> 6;
    const int lane = tid & 63;

    // ---- phase 0: zero WpT2 region, load image block ----
    for (int idx = tid; idx < 5280; idx += 256) U[idx] = 0.0f;
    const float* src = imgs + ((size_t)n * IMG_H + bh * BLK) * IMG_W + bw * BLK;
    for (int idx = tid; idx < BLK * BLK; idx += 256)
        blk_s[idx] = src[(idx >> 5) * IMG_W + (idx & 31)];
    __syncthreads();

    // ---- phase 1: build Wp (2x2-aggregated PSF), b fast for coalescing ----
    const float* psfp = psf + (size_t)p * PSFN * PSFN;
    for (int idx = tid; idx < 65 * 65; idx += 256) {
        int bi = idx % 65;              // b+1 (fast -> coalesced psf reads)
        int ai = idx / 65;              // a+1
        int a = ai - 1, b = bi - 1;
        float s = 0.0f;
        #pragma unroll
        for (int du = 0; du < 2; ++du)
            #pragma unroll
            for (int dv = 0; dv < 2; ++dv) {
                int x = a + du, y = b + dv;
                if ((unsigned)x < 64u && (unsigned)y < 64u)
                    s += psfp[x * PSFN + y];
            }
        int row = b + 8;
        U[(row >> 1) * WPSTRIDE + ai * 2 + (row & 1)] = s;
    }
    __syncthreads();

    // ---- phase 2: register weights (a = lane) + ghost line ----
    float2 w[33];
    #pragma unroll
    for (int q = 0; q < 33; ++q)
        w[q] = *(const float2*)&U[(q + 3) * WPSTRIDE + (lane + 1) * 2];
    #pragma unroll
    for (int q = 0; q < 33; ++q)
        asm volatile("" : "+v"(w[q].x), "+v"(w[q].y));   // pin in VGPRs
    {
        int b = tid - 64;               // garr[k] = Wp[-1][k-64]
        float v = 0.0f;
        if (b >= -1 && b <= 63) {
            int row = b + 8;
            v = U[(row >> 1) * WPSTRIDE + (row & 1)];    // acol = 0
        }
        if (tid < 192) garr[tid] = v;
    }
    __syncthreads();

    // ---- phase 3: zero the output accumulator (overlays WpT2) ----
    for (int idx = tid; idx < UNION_FLOATS; idx += 256) U[idx] = 0.0f;
    __syncthreads();

    // ---- phase 4: main accumulation ----
    switch (wv) {
    case 0:  main_loop<0>(U, blk_s, w, lane); break;
    case 1:  main_loop<1>(U, blk_s, w, lane); break;
    case 2:  main_loop<2>(U, blk_s, w, lane); break;
    default: main_loop<3>(U, blk_s, w, lane); break;
    }

    // ---- phase 5: ghost a = -1 -> rows i = 2r+64 (safe via ds atomics) ----
    #pragma unroll
    for (int jh = 0; jh < 2; ++jh) {
        const int j = jh * 64 + lane;
        float gw[32];
        #pragma unroll
        for (int c = 0; c < 32; ++c) gw[c] = garr[2 * c + 127 - j];
        for (int rr = wv; rr < 32; rr += 4) {
            float acc = 0.0f;
            #pragma unroll
            for (int c = 0; c < 32; ++c)
                acc = fmaf(blk_s[rr * 32 + c], gw[c], acc);
            atomicAdd(&U[(2 * rr + 64) * SJ + j], acc);
        }
    }
    __syncthreads();

    // ---- phase 6: merge ----
    if (use_ws) {
        float* tile = ws + (size_t)(n * P_CNT + p) * TILE_FLOATS;
        for (int idx = tid; idx < TILE_FLOATS; idx += 256)
            tile[idx] = U[(idx >> 7) * SJ + (idx & 127)];
    } else {
        const int icen = 176 + 48 * bh;
        const int jcen = 176 + 48 * bw;
        float* outn = out + ((size_t)n << 20);
        for (int idx = tid; idx < TILE_FLOATS; idx += 256) {
            const int i = idx >> 7, j = idx & 127;
            atomicAdd(&outn[(size_t)(icen - 63 + i) * SENS + (jcen - 63 + j)],
                      U[i * SJ + j]);
        }
    }
}

// Each sensor pixel sums its <=3x3 contributing region tiles. Pure reads.
__global__ __launch_bounds__(256) void svconv_gather(
    const float* __restrict__ ws, float* __restrict__ out)
{
    const int b = blockIdx.x;           // 8 n * 1024 x-rows
    const int n = b >> 10, x = b & 1023;
    int bhlo = (x + 288) / 48 - 10; if (bhlo < 0) bhlo = 0;   // ceil((x-239)/48)
    int bhhi = (x < 113) ? -1 : ((x - 113) / 48);
    if (bhhi > 15) bhhi = 15;
    if (bhlo > bhhi) return;            // row untouched by any region (stays 0)
    const float* wsn = ws + (size_t)n * P_CNT * TILE_FLOATS;
    float* outrow = out + ((size_t)n << 20) + (size_t)x * SENS;

    for (int yb = 0; yb < 4; ++yb) {
        const int y = yb * 256 + threadIdx.x;
        int bwlo = (y + 288) / 48 - 10; if (bwlo < 0) bwlo = 0;
        int bwhi = (y < 113) ? -1 : ((y - 113) / 48);
        if (bwhi > 15) bwhi = 15;
        float s = 0.0f;
        for (int bh = bhlo; bh <= bhhi; ++bh) {
            const int ti = x - (176 + 48 * bh) + 63;          // 0..126
            #pragma unroll
            for (int k = 0; k < 3; ++k) {
                const int bw = bwlo + k;
                if (bw <= bwhi) {
                    const int tj = y - 113 - 48 * bw;         // 0..126
                    s += wsn[(size_t)(bw * 16 + bh) * TILE_FLOATS + ti * TJ + tj];
                }
            }
        }
        outrow[y] = s;
    }
}

extern "C" void kernel_launch(void* const* d_in, const int* in_sizes, int n_in,
                              void* d_out, int out_size, void* d_ws, size_t ws_size,
                              hipStream_t stream) {
    const float* imgs = (const float*)d_in[0];
    const float* psf  = (const float*)d_in[1];
    float* out = (float*)d_out;
    const int use_ws = (ws_size >= WS_NEED) ? 1 : 0;

    hipMemsetAsync(out, 0, (size_t)out_size * sizeof(float), stream);
    svconv_tiles<<<dim3(IMG_N * P_CNT), dim3(256), 0, stream>>>(
        imgs, psf, (float*)d_ws, out, use_ws);
    if (use_ws)
        svconv_gather<<<dim3(IMG_N * SENS), dim3(256), 0, stream>>>(
            (const float*)d_ws, out);
}

// Round 6
// 427.009 us; speedup vs baseline: 6.7053x; 6.7053x over previous
//
#include <hip/hip_runtime.h>

#define IMG_N 8
#define IMG_H 512
#define IMG_W 512
#define P_CNT 256
#define PSFN  64
#define SENS  1024

// K storage (staged in d_out; gather overwrites every output pixel later):
// Kd[p][cls][f][e], cls = pi*2+pj. e-stride 36 (16B-aligned rows), 33 f-rows.
#define KF_STRIDE   36
#define KCLS_STRIDE (33 * KF_STRIDE)     // 1188
#define KP_STRIDE   (4 * KCLS_STRIDE)    // 4752 floats per region

// ws tiles, planar parity layout per (n,p):
// class00 64x64 @0, class01 64x63 @4096, class10 63x64 @8128, class11 63x63 @12160
#define TILE_FLOATS 16129
#define WS_NEED ((size_t)IMG_N * P_CNT * TILE_FLOATS * sizeof(float))

// blkT[c+32][r]: transposed image block, c in [-32,63] zero-padded, stride 34
#define BT_STRIDE 34
#define BT_ROWS   96

// ---------------- prep: build parity-decimated 2x2-aggregated PSF ----------
__global__ __launch_bounds__(256) void svconv_prep(
    const float* __restrict__ psf, float* __restrict__ kd)
{
    __shared__ float ps[PSFN * PSFN];
    const int p = blockIdx.x, tid = threadIdx.x;
    const float* psp = psf + (size_t)p * PSFN * PSFN;
    for (int i = tid; i < PSFN * PSFN; i += 256) ps[i] = psp[i];
    __syncthreads();
    float* kp = kd + (size_t)p * KP_STRIDE;
    for (int idx = tid; idx < KP_STRIDE; idx += 256) {
        const int cls = idx / KCLS_STRIDE;
        const int rem = idx - cls * KCLS_STRIDE;
        const int f = rem / KF_STRIDE;
        const int e = rem - f * KF_STRIDE;
        const int pi = cls >> 1, pj = cls & 1;
        const int E = pi ? 32 : 33, F = pj ? 32 : 33;
        float v = 0.0f;
        if (e < E && f < F) {
            const int a = pi ? 2 * e : 2 * e - 1;   // Wp row
            const int b = pj ? 2 * f : 2 * f - 1;   // Wp col
            #pragma unroll
            for (int du = 0; du < 2; ++du)
                #pragma unroll
                for (int dv = 0; dv < 2; ++dv) {
                    const int x = a + du, y = b + dv;
                    if ((unsigned)x < 64u && (unsigned)y < 64u)
                        v += ps[x * PSFN + y];
                }
        }
        kp[idx] = v;
    }
}

// ---------------- main: per-class conv, output-stationary registers --------
template<int PI, int PJ>
__device__ __forceinline__ void class_compute(
    const float* __restrict__ blkT, const float* __restrict__ kcls,
    float* __restrict__ tile, const int lane)
{
    constexpr int E   = PI ? 32 : 33;
    constexpr int F   = PJ ? 32 : 33;
    constexpr int U0  = PI ? 31 : 32;
    constexpr int V0  = PJ ? 31 : 32;
    constexpr int NU  = PI ? 63 : 64;     // valid u rows
    constexpr int CSTR = PJ ? 63 : 64;    // plane row stride
    constexpr int COFF = (PI ? 8128 : 0) + (PJ ? (PI ? 4032 : 4096) : 0);

    float acc[NU];
    #pragma unroll
    for (int u = 0; u < NU; ++u) acc[u] = 0.0f;

    const float* bp = blkT + (lane - V0 + 32) * BT_STRIDE;   // row c = lane+f-V0
    for (int f = 0; f < F; ++f) {
        // wave-uniform weight column K[0..E-1][f] -> scalar regs
        const float* kc = kcls + f * KF_STRIDE;
        float w[E];
        #pragma unroll
        for (int e = 0; e < E; ++e) w[e] = kc[e];
        // lane's blk column (c fixed this f): 32 values, b64 LDS reads
        float bc[32];
        #pragma unroll
        for (int k = 0; k < 16; ++k) {
            const float2 t = *(const float2*)&bp[2 * k];
            bc[2 * k] = t.x; bc[2 * k + 1] = t.y;
        }
        // all (e,r) combos valid: u = r-e+U0 in [0,NU-1] by construction
        #pragma unroll
        for (int e = 0; e < E; ++e)
            #pragma unroll
            for (int r = 0; r < 32; ++r)
                acc[r - e + U0] = fmaf(w[e], bc[r], acc[r - e + U0]);
        bp += BT_STRIDE;
    }

    if (PJ == 0 || lane < 63) {           // lane63 of pj=1 -> j=127, discard
        float* tp = tile + COFF + lane;
        #pragma unroll
        for (int u = 0; u < NU; ++u) tp[u * CSTR] = acc[u];
    }
}

__global__ __launch_bounds__(256, 2) void svconv_main(
    const float* __restrict__ imgs, const float* __restrict__ kd,
    float* __restrict__ ws)
{
    __shared__ float blkT[BT_ROWS * BT_STRIDE];
    const int bid = blockIdx.x;
    const int n = bid >> 8, p = bid & 255;
    const int bh = p & 15, bw = p >> 4;
    const int tid = threadIdx.x;

    for (int i = tid; i < BT_ROWS * BT_STRIDE; i += 256) blkT[i] = 0.0f;
    __syncthreads();
    const float* src = imgs + ((size_t)n * IMG_H + bh * 32) * IMG_W + bw * 32;
    {
        const int r0 = tid >> 5, c = tid & 31;
        for (int r = r0; r < 32; r += 8)
            blkT[(c + 32) * BT_STRIDE + r] = src[r * IMG_W + c];
    }
    __syncthreads();

    const int wv = tid >> 6, lane = tid & 63;
    // readfirstlane -> provably wave-uniform offset -> scalar (s_load) weights
    const int koff = __builtin_amdgcn_readfirstlane(p * KP_STRIDE + wv * KCLS_STRIDE);
    const float* kcls = kd + koff;
    float* tile = ws + (size_t)(n * P_CNT + p) * TILE_FLOATS;

    switch (wv) {
    case 0:  class_compute<0, 0>(blkT, kcls, tile, lane); break;
    case 1:  class_compute<0, 1>(blkT, kcls, tile, lane); break;
    case 2:  class_compute<1, 0>(blkT, kcls, tile, lane); break;
    default: class_compute<1, 1>(blkT, kcls, tile, lane); break;
    }
}

// ---------------- gather: sensor pixel sums <=3x3 overlapping tiles --------
__global__ __launch_bounds__(256) void svconv_gather(
    const float* __restrict__ ws, float* __restrict__ out)
{
    const int b = blockIdx.x;
    const int n = b >> 10, x = b & 1023;
    int bhlo = (x + 288) / 48 - 10; if (bhlo < 0) bhlo = 0;
    int bhhi = (x < 113) ? -1 : ((x - 113) / 48);
    if (bhhi > 15) bhhi = 15;
    const float* wsn = ws + (size_t)n * P_CNT * TILE_FLOATS;
    float* outrow = out + ((size_t)n << 20) + (size_t)x * SENS;

    for (int yb = 0; yb < 4; ++yb) {
        const int y = yb * 256 + threadIdx.x;
        int bwlo = (y + 288) / 48 - 10; if (bwlo < 0) bwlo = 0;
        int bwhi = (y < 113) ? -1 : ((y - 113) / 48);
        if (bwhi > 15) bwhi = 15;
        float s = 0.0f;
        for (int bh = bhlo; bh <= bhhi; ++bh) {
            const int ti = x - 113 - 48 * bh;          // 0..126
            const int pi = ti & 1, uu = ti >> 1;
            #pragma unroll
            for (int k = 0; k < 3; ++k) {
                const int bw = bwlo + k;
                if (bw <= bwhi) {
                    const int tj = y - 113 - 48 * bw;  // 0..126
                    const int pj = tj & 1, vv = tj >> 1;
                    const int off = (pi ? 8128 : 0) + (pj ? (pi ? 4032 : 4096) : 0);
                    const int cstr = pj ? 63 : 64;
                    s += wsn[(size_t)(bw * 16 + bh) * TILE_FLOATS + off + uu * cstr + vv];
                }
            }
        }
        outrow[y] = s;   // unconditional: d_out temporarily holds K, overwrite all
    }
}

extern "C" void kernel_launch(void* const* d_in, const int* in_sizes, int n_in,
                              void* d_out, int out_size, void* d_ws, size_t ws_size,
                              hipStream_t stream) {
    const float* imgs = (const float*)d_in[0];
    const float* psf  = (const float*)d_in[1];
    float* out = (float*)d_out;
    float* kd  = (float*)d_out;          // K staged in d_out (4.9 MB << 33.5 MB)
    float* ws  = (float*)d_ws;           // tiles: 132.1 MB (< R5-proven 133.2 MB)

    svconv_prep<<<dim3(P_CNT), dim3(256), 0, stream>>>(psf, kd);
    svconv_main<<<dim3(IMG_N * P_CNT), dim3(256), 0, stream>>>(imgs, kd, ws);
    svconv_gather<<<dim3(IMG_N * SENS), dim3(256), 0, stream>>>(ws, out);
}

// Round 7
// 388.195 us; speedup vs baseline: 7.3758x; 1.1000x over previous
//
#include <hip/hip_runtime.h>

typedef float v2f __attribute__((ext_vector_type(2)));

#define IMG_N 8
#define IMG_H 512
#define IMG_W 512
#define P_CNT 256
#define PSFN  64
#define SENS  1024

// Packed weights Kp[p]: float2 entries (K_{pi,pj=0}[e][g], K_{pi,pj=1}[e][g-1]).
// pi=0 plane: g in [0,33), e in [0,33)  -> 1089 entries, idx = g*33+e
// pi=1 plane: g in [0,33), e in [0,32)  -> 1056 entries, idx = 1089 + g*32+e
#define KP_STRIDE 2145          // float2 per region
// ws tile per (n,p): plane pi=0: 64u x 64v float2 (8192 fl); pi=1: 63u x 64v (8064 fl)
#define TILE_FLOATS 16256
#define BT_STRIDE 34            // blkT[c+32][r], c in [-32,63], zero-padded

// ---------------- prep: packed parity-decimated 2x2-aggregated PSF ---------
__global__ __launch_bounds__(256) void svconv_prep(
    const float* __restrict__ psf, float* __restrict__ kd)
{
    __shared__ float ps[PSFN * PSFN];
    const int p = blockIdx.x, tid = threadIdx.x;
    const float* psp = psf + (size_t)p * PSFN * PSFN;
    for (int i = tid; i < PSFN * PSFN; i += 256) ps[i] = psp[i];
    __syncthreads();
    v2f* kp = (v2f*)kd + (size_t)p * KP_STRIDE;
    for (int idx = tid; idx < KP_STRIDE; idx += 256) {
        int pi, g, e;
        if (idx < 1089) { pi = 0; g = idx / 33; e = idx - g * 33; }
        else            { pi = 1; int t = idx - 1089; g = t / 32; e = t - g * 32; }
        const int a = pi ? 2 * e : 2 * e - 1;
        float w[2];
        #pragma unroll
        for (int h = 0; h < 2; ++h) {
            const int b = 2 * g - 1 - h;        // h=0: pj=0 (f=g); h=1: pj=1 (f=g-1)
            float s = 0.0f;
            #pragma unroll
            for (int du = 0; du < 2; ++du)
                #pragma unroll
                for (int dv = 0; dv < 2; ++dv) {
                    const int x = a + du, y = b + dv;
                    if ((unsigned)x < 64u && (unsigned)y < 64u) s += ps[x * PSFN + y];
                }
            w[h] = s;
        }
        kp[idx] = (v2f){w[0], w[1]};
    }
}

// ---------------- main: packed per-(pi, g-half) conv -----------------------
// Lane <-> output column v. acc2[u] = (out[2u+pi][2v], out[2u+pi][2v+1]).
// u = r - e + U0 always in range (dense in e,r). c = v+g-32 handled by blkT pad.
// GH=1 wave writes partials to mrg; GH=0 partner adds + stores tile.
template<int PI, int GH>
__device__ __forceinline__ void cls_compute(
    const float* __restrict__ blkT, const v2f* __restrict__ kp,
    v2f* mrg, v2f* tilep, const int lane)
{
    constexpr int E  = PI ? 32 : 33;
    constexpr int U0 = PI ? 31 : 32;
    constexpr int NU = PI ? 63 : 64;
    constexpr int G0 = GH ? 17 : 0;
    constexpr int G1 = GH ? 33 : 17;

    v2f acc[NU];
    #pragma unroll
    for (int u = 0; u < NU; ++u) acc[u] = (v2f){0.f, 0.f};

    for (int g = G0; g < G1; ++g) {
        const v2f* wrow = kp + g * E;           // wave-uniform -> s_load
        v2f w2[E];
        #pragma unroll
        for (int e = 0; e < E; ++e) w2[e] = wrow[e];
        const float* bp = blkT + (lane + g) * BT_STRIDE;   // column c = lane+g-32
        v2f bcv[16];
        #pragma unroll
        for (int k = 0; k < 16; ++k) bcv[k] = *(const v2f*)&bp[2 * k];
        #pragma unroll
        for (int r = 0; r < 32; ++r) {
            const float bs = (r & 1) ? bcv[r >> 1].y : bcv[r >> 1].x;
            const v2f bb = (v2f){bs, bs};       // built once per r, reused over e
            #pragma unroll
            for (int e = 0; e < E; ++e)
                acc[r - e + U0] = __builtin_elementwise_fma(w2[e], bb, acc[r - e + U0]);
        }
    }

    if (GH) {
        #pragma unroll
        for (int u = 0; u < NU; ++u) mrg[u * 64 + lane] = acc[u];
    }
    __syncthreads();   // every wave executes exactly one barrier here
    if (!GH) {
        #pragma unroll
        for (int u = 0; u < NU; ++u)
            tilep[u * 64 + lane] = mrg[u * 64 + lane] + acc[u];
    }
}

__global__ __launch_bounds__(256, 2) void svconv_main(
    const float* __restrict__ imgs, const float* __restrict__ kd,
    float* __restrict__ ws)
{
    __shared__ float blkT[96 * BT_STRIDE];   // 13056 B (separate from mrg: no race)
    __shared__ v2f   mrg[8128];              // 65024 B; plane0 @0 (4096), plane1 @4096

    const int bid = blockIdx.x;
    const int n = bid >> 8, p = bid & 255;
    const int bh = p & 15, bw = p >> 4;
    const int tid = threadIdx.x;

    for (int i = tid; i < 96 * BT_STRIDE; i += 256) blkT[i] = 0.0f;
    __syncthreads();
    const float* src = imgs + ((size_t)n * IMG_H + bh * 32) * IMG_W + bw * 32;
    {
        const int r0 = tid >> 5, c = tid & 31;
        for (int r = r0; r < 32; r += 8)
            blkT[(c + 32) * BT_STRIDE + r] = src[r * IMG_W + c];
    }
    __syncthreads();

    const int wv = tid >> 6, lane = tid & 63;
    v2f* tile = (v2f*)(ws + (size_t)(n * P_CNT + p) * TILE_FLOATS);
    const v2f* kbase = (const v2f*)kd;

    switch (wv) {
    case 0: {
        const v2f* kp = kbase + __builtin_amdgcn_readfirstlane(p * KP_STRIDE);
        cls_compute<0, 0>(blkT, kp, mrg, tile, lane);
    } break;
    case 1: {
        const v2f* kp = kbase + __builtin_amdgcn_readfirstlane(p * KP_STRIDE);
        cls_compute<0, 1>(blkT, kp, mrg, tile, lane);
    } break;
    case 2: {
        const v2f* kp = kbase + __builtin_amdgcn_readfirstlane(p * KP_STRIDE + 1089);
        cls_compute<1, 0>(blkT, kp, mrg + 4096, tile + 4096, lane);
    } break;
    default: {
        const v2f* kp = kbase + __builtin_amdgcn_readfirstlane(p * KP_STRIDE + 1089);
        cls_compute<1, 1>(blkT, kp, mrg + 4096, tile + 4096, lane);
    } break;
    }
}

// ---------------- gather: every pixel written (no stale-data early-out) ----
__global__ __launch_bounds__(256) void svconv_gather(
    const float* __restrict__ ws, float* __restrict__ out)
{
    const int b = blockIdx.x;
    const int n = b >> 10, x = b & 1023;
    int bhlo = (x + 288) / 48 - 10; if (bhlo < 0) bhlo = 0;
    int bhhi = (x < 113) ? -1 : ((x - 113) / 48);
    if (bhhi > 15) bhhi = 15;
    const float* wsn = ws + (size_t)n * P_CNT * TILE_FLOATS;
    float* outrow = out + ((size_t)n << 20) + (size_t)x * SENS;

    for (int yb = 0; yb < 4; ++yb) {
        const int y = yb * 256 + threadIdx.x;
        int bwlo = (y + 288) / 48 - 10; if (bwlo < 0) bwlo = 0;
        int bwhi = (y < 113) ? -1 : ((y - 113) / 48);
        if (bwhi > 15) bwhi = 15;
        float s = 0.0f;
        for (int bh = bhlo; bh <= bhhi; ++bh) {
            const int ti = x - 113 - 48 * bh;              // 0..126
            const int pi = ti & 1, uu = ti >> 1;
            #pragma unroll
            for (int k = 0; k < 3; ++k) {
                const int bw = bwlo + k;
                if (bw <= bwhi) {
                    const int tj = y - 113 - 48 * bw;      // 0..126
                    const int pj = tj & 1, vv = tj >> 1;
                    s += wsn[(size_t)(bw * 16 + bh) * TILE_FLOATS
                             + pi * 8192 + (uu * 64 + vv) * 2 + pj];
                }
            }
        }
        outrow[y] = s;   // unconditional: overwrites K staging & poison everywhere
    }
}

extern "C" void kernel_launch(void* const* d_in, const int* in_sizes, int n_in,
                              void* d_out, int out_size, void* d_ws, size_t ws_size,
                              hipStream_t stream) {
    const float* imgs = (const float*)d_in[0];
    const float* psf  = (const float*)d_in[1];
    float* out = (float*)d_out;
    float* kd  = (float*)d_out;   // K staged in d_out (4.4 MB << 33.5 MB); gather overwrites
    float* ws  = (float*)d_ws;    // tiles: 133.17 MB (R5-proven fit)

    svconv_prep<<<dim3(P_CNT), dim3(256), 0, stream>>>(psf, kd);
    svconv_main<<<dim3(IMG_N * P_CNT), dim3(256), 0, stream>>>(imgs, kd, ws);
    svconv_gather<<<dim3(IMG_N * SENS), dim3(256), 0, stream>>>(ws, out);
}

// Round 9
// 215.500 us; speedup vs baseline: 13.2865x; 1.8014x over previous
//
#include <hip/hip_runtime.h>

typedef _Float16 h8 __attribute__((ext_vector_type(8)));
typedef float    f4 __attribute__((ext_vector_type(4)));
typedef unsigned int u4 __attribute__((ext_vector_type(4)));

#define IMG_N 8
#define IMG_H 512
#define IMG_W 512
#define P_CNT 256
#define PSFN  64
#define SENS  1024
#define TILE_FLOATS 16256   // planes: (0,0)@0 4096, (0,1)@4096 4096, (1,0)@8192 4032, (1,1)@12224 4032

// Kt: [cls][g][copy s][104] fp16.  copy_s[i] = row[t=i+s]; row[t] = K[e=t-32][g]
// (zero outside e in [0,E)).  Reads: t0 = 8q - m + (U0-16ut) + 32, s = t0&1,
// 4x b32 at even half-index t0-s  -> always 4B-aligned LDS loads.
#define KT_HALVES (4*33*2*104)   // 27456 (54912 B)
// BpadT: [97 cols][40 r] fp16, col = c+32 (c in [-32,64], zero-padded outside
// [0,32)).  97th col: pj=1,g=32,v=63 reads c=64 (zero).  Stride 80 B: aligned b128.
#define BT_COLS   97
#define BT_HALVES (BT_COLS*40)   // 3880 (7760 B)

__global__ __launch_bounds__(256, 2) void svconv_main(
    const float* __restrict__ imgs, const float* __restrict__ psf,
    float* __restrict__ ws)
{
    __shared__ float ps[PSFN * PSFN];                   // 16384 B
    __shared__ __align__(16) _Float16 Kt[KT_HALVES];    // 54912 B
    __shared__ __align__(16) _Float16 BT[BT_HALVES];    //  7760 B  -> 79056 B total

    const int bid = blockIdx.x;
    const int n = bid >> 8, p = bid & 255;
    const int bh = p & 15, bw = p >> 4;      // bh pairs with i/x, bw with j/y
    const int tid = threadIdx.x;
    const int wv = tid >> 6, lane = tid & 63;
    const int m = lane & 15, q = lane >> 4;

    // ---- phase 0: stage psf, zero Kt/BT ----
    {
        const float4* pp = (const float4*)(psf + (size_t)p * PSFN * PSFN);
        float4* pd = (float4*)ps;
        for (int i = tid; i < PSFN * PSFN / 4; i += 256) pd[i] = pp[i];
        const u4 z = {0u, 0u, 0u, 0u};
        u4* kz = (u4*)Kt;
        for (int i = tid; i < KT_HALVES / 8; i += 256) kz[i] = z;
        for (int i = tid; i < BT_HALVES; i += 256) BT[i] = (_Float16)0.f;
    }
    __syncthreads();

    // ---- phase 1: fill valid Kt entries (both copies) + BT block columns ----
    // K_cls[e][g] = Wp[a=2e-1+pi][b=2g-1+pj], Wp = 2x2-aggregated psf.
    // Verified index algebra: i=2u+pi, j=2v+pj =>
    //   e = r-u+U0 (U0 = pi?31:32), X column c = v+g-32+pj  <-- pj term (R8 bug fix)
    for (int idx = tid; idx < 4 * 33 * 33; idx += 256) {
        const int e = idx % 33;
        const int gc = idx / 33;
        const int g = gc % 33;
        const int cls = gc / 33;
        const int pi = cls >> 1, pj = cls & 1;
        const int E = pi ? 32 : 33;
        if (e < E) {
            const int a = 2 * e - 1 + pi;
            const int b = 2 * g - 1 + pj;
            float sv = 0.f;
            #pragma unroll
            for (int du = 0; du < 2; ++du) {
                const int x = a + du;
                if ((unsigned)x < 64u) {
                    #pragma unroll
                    for (int dv = 0; dv < 2; ++dv) {
                        const int y = b + dv;
                        if ((unsigned)y < 64u) sv += ps[x * 64 + y];
                    }
                }
            }
            const _Float16 hv = (_Float16)sv;
            const int base = (cls * 33 + g) * 208;   // halves: 2 copies * 104
            const int t = e + 32;
            Kt[base + t]           = hv;   // copy0, i = t
            Kt[base + 104 + t - 1] = hv;   // copy1, i = t-1
        }
    }
    {
        const int r0 = tid >> 5, c = tid & 31;
        const float* src = imgs + ((size_t)n * IMG_H + bh * 32) * IMG_W + bw * 32;
        for (int r = r0; r < 32; r += 8)
            BT[(c + 32) * 40 + r] = (_Float16)src[r * IMG_W + c];
    }
    __syncthreads();

    // ---- main: wave = class (pi,pj); D[u][v] = sum_g W_g * X_g via MFMA ----
    const int cls = wv, pi = cls >> 1, pj = cls & 1;
    const int U0 = pi ? 31 : 32;
    const char* ktc = (const char*)Kt;
    const char* btc = (const char*)BT + pj * 80;   // pj=1: column +1 (c = v+g-31)

    int aoff[4];
    #pragma unroll
    for (int ut = 0; ut < 4; ++ut) {
        const int t0 = 8 * q - m + (U0 - 16 * ut) + 32;   // in [0,88]
        const int s  = t0 & 1;
        aoff[ut] = (cls * 33) * 416 + s * 208 + (t0 - s) * 2;   // byte offset
    }
    int boff[4];
    #pragma unroll
    for (int vt = 0; vt < 4; ++vt) boff[vt] = (16 * vt + m) * 80 + q * 16;

    f4 acc[4][4];
    #pragma unroll
    for (int ut = 0; ut < 4; ++ut)
        #pragma unroll
        for (int vt = 0; vt < 4; ++vt) acc[ut][vt] = (f4){0.f, 0.f, 0.f, 0.f};

    #pragma unroll 1
    for (int g = 0; g < 33; ++g) {
        h8 B[4];
        #pragma unroll
        for (int vt = 0; vt < 4; ++vt)
            B[vt] = *(const h8*)(btc + boff[vt] + g * 80);   // aligned b128
        h8 A[4];
        #pragma unroll
        for (int ut = 0; ut < 4; ++ut) {
            const unsigned* ap = (const unsigned*)(ktc + aoff[ut] + g * 416);
            u4 d = {ap[0], ap[1], ap[2], ap[3]};             // 4x b32 (even idx)
            A[ut] = __builtin_bit_cast(h8, d);
        }
        #pragma unroll
        for (int ut = 0; ut < 4; ++ut)
            #pragma unroll
            for (int vt = 0; vt < 4; ++vt)
                acc[ut][vt] = __builtin_amdgcn_mfma_f32_16x16x32_f16(
                    A[ut], B[vt], acc[ut][vt], 0, 0, 0);
    }

    // ---- epilogue: C/D col=lane&15 (v), row=quad*4+reg (u); store planar ----
    float* tile = ws + (size_t)(n * P_CNT + p) * TILE_FLOATS;
    const int plane = pi ? (8192 + pj * 4032) : (pj * 4096);
    #pragma unroll
    for (int ut = 0; ut < 4; ++ut) {
        #pragma unroll
        for (int reg = 0; reg < 4; ++reg) {
            const int u = 16 * ut + 4 * q + reg;
            if (pi == 0 || u < 63) {                 // pi=1 u=63 -> i=127 discard
                float* rp = tile + plane + u * 64 + m;
                #pragma unroll
                for (int vt = 0; vt < 4; ++vt) rp[16 * vt] = acc[ut][vt][reg];
            }
        }
    }
}

// ---- gather: every pixel written unconditionally (no stale-poison paths) ----
__global__ __launch_bounds__(256) void svconv_gather(
    const float* __restrict__ ws, float* __restrict__ out)
{
    const int b = blockIdx.x;
    const int n = b >> 10, x = b & 1023;
    int bhlo = (x + 288) / 48 - 10; if (bhlo < 0) bhlo = 0;
    int bhhi = (x < 113) ? -1 : ((x - 113) / 48);
    if (bhhi > 15) bhhi = 15;
    const float* wsn = ws + (size_t)n * P_CNT * TILE_FLOATS;
    float* outrow = out + ((size_t)n << 20) + (size_t)x * SENS;

    for (int yb = 0; yb < 4; ++yb) {
        const int y = yb * 256 + threadIdx.x;
        int bwlo = (y + 288) / 48 - 10; if (bwlo < 0) bwlo = 0;
        int bwhi = (y < 113) ? -1 : ((y - 113) / 48);
        if (bwhi > 15) bwhi = 15;
        float s = 0.0f;
        for (int bhh = bhlo; bhh <= bhhi; ++bhh) {
            const int ti = x - 113 - 48 * bhh;          // 0..126
            const int pi = ti & 1, uu = ti >> 1;
            for (int bww = bwlo; bww <= bwhi; ++bww) {
                const int tj = y - 113 - 48 * bww;      // 0..126
                const int pj = tj & 1, vv = tj >> 1;
                const int base = pi ? (8192 + pj * 4032) : (pj * 4096);
                s += wsn[(size_t)(bww * 16 + bhh) * TILE_FLOATS + base + uu * 64 + vv];
            }
        }
        outrow[y] = s;   // uncovered pixels get exact 0
    }
}

extern "C" void kernel_launch(void* const* d_in, const int* in_sizes, int n_in,
                              void* d_out, int out_size, void* d_ws, size_t ws_size,
                              hipStream_t stream) {
    const float* imgs = (const float*)d_in[0];
    const float* psf  = (const float*)d_in[1];
    float* out = (float*)d_out;
    float* ws  = (float*)d_ws;    // tiles: 8*256*16256*4 = 133.17 MB (R5-proven fit)

    svconv_main<<<dim3(IMG_N * P_CNT), dim3(256), 0, stream>>>(imgs, psf, ws);
    svconv_gather<<<dim3(IMG_N * SENS), dim3(256), 0, stream>>>(ws, out);
}